// Round 1
// baseline (210.102 us; speedup 1.0000x reference)
//
#include <hip/hip_runtime.h>

#define S_DIM 512
#define B_DIM 16384
#define A_DIM 2
#define BA (B_DIM * A_DIM)   // 32768
#define HID 16
#define EMB 8
#define NPART 1000
#define TABN (NPART * HID)   // 16000

// Kernel 1: emb_proj[p][j] = b1[j] + sum_k emb_table[p][k] * W1[2+k][j]
__global__ __launch_bounds__(256) void emb_proj_kernel(
    const float* __restrict__ emb_table, const float* __restrict__ W1,
    const float* __restrict__ b1, float* __restrict__ proj) {
  int idx = blockIdx.x * 256 + threadIdx.x;
  if (idx >= TABN) return;
  int p = idx >> 4;
  int j = idx & 15;
  float acc = b1[j];
#pragma unroll
  for (int k = 0; k < EMB; ++k)
    acc = fmaf(emb_table[p * EMB + k], W1[(2 + k) * HID + j], acc);
  proj[idx] = acc;
}

// Kernel 2: the sequential scan. 4 lanes per (b,a) chain, 4 hidden units each.
__global__ __launch_bounds__(256) void scan_kernel(
    const int* __restrict__ act, const float* __restrict__ rew,
    const int* __restrict__ pid, const float* __restrict__ W1,
    const float* __restrict__ W2, const float* __restrict__ b2,
    const float* __restrict__ proj, float* __restrict__ out) {
  __shared__ float tab[TABN];
  int tid = threadIdx.x;
  for (int i = tid; i < TABN; i += 256) tab[i] = proj[i];
  __syncthreads();

  int t = blockIdx.x * 256 + tid;   // 0 .. 131071
  int chain = t >> 2;               // 0 .. 32767  (= b*A + a)
  int sub = t & 3;                  // which 4-unit group of HID=16
  int b = chain >> 1;
  int j0 = sub << 2;

  float w1a[4], w1b[4], w2v[4];
#pragma unroll
  for (int jj = 0; jj < 4; ++jj) {
    w1a[jj] = W1[j0 + jj];           // W1[0][j]
    w1b[jj] = W1[HID + j0 + jj];     // W1[1][j]
    w2v[jj] = W2[j0 + jj];           // W2[j][0]
  }
  float bb2 = b2[0];
  float state = 0.f;

  const float* rp = rew + chain;
  const int* ap = act + chain;
  const int* pp = pid + b;

  // software-pipeline the global loads one step ahead
  float r_nxt = rp[0];
  int a_nxt = ap[0];
  int p_nxt = pp[0];

  for (int s = 0; s < S_DIM; ++s) {
    float r = r_nxt;
    int a = a_nxt;
    int pd = p_nxt;
    if (s + 1 < S_DIM) {
      r_nxt = rp[(size_t)(s + 1) * BA];
      a_nxt = ap[(size_t)(s + 1) * BA];
      p_nxt = pp[(size_t)(s + 1) * B_DIM];
    }
    float4 pre = *(const float4*)(tab + pd * HID + j0);
    float pr[4] = {pre.x, pre.y, pre.z, pre.w};
    float psum = 0.f;
#pragma unroll
    for (int jj = 0; jj < 4; ++jj) {
      // x = state*W1[0,j] + r*W1[1,j] + emb_proj[pid][j]
      float x = fmaf(state, w1a[jj], fmaf(r, w1b[jj], pr[jj]));
      // relu(tanh(x)) == tanh(max(x,0))
      x = fmaxf(x, 0.f);
      float e = __builtin_amdgcn_exp2f(x * 2.8853900817779268f);  // exp(2x)
      float h = 1.f - 2.f * __builtin_amdgcn_rcpf(e + 1.f);       // tanh(x)
      psum = fmaf(h, w2v[jj], psum);
    }
    // reduce the 16->1 dot across the chain's 4 lanes
    psum += __shfl_xor(psum, 1);
    psum += __shfl_xor(psum, 2);
    float z = state + ((a == 1) ? (psum + bb2) : 0.f);
    // sigmoid(z)
    state = __builtin_amdgcn_rcpf(1.f + __builtin_amdgcn_exp2f(z * -1.4426950408889634f));
    if (sub == 0) out[(size_t)s * BA + chain] = state;
  }
}

extern "C" void kernel_launch(void* const* d_in, const int* in_sizes, int n_in,
                              void* d_out, int out_size, void* d_ws, size_t ws_size,
                              hipStream_t stream) {
  const int* c_Action = (const int*)d_in[0];
  const float* c_Reward = (const float*)d_in[1];
  const int* c_ParticipantID = (const int*)d_in[2];
  const float* emb_table = (const float*)d_in[3];
  const float* W1 = (const float*)d_in[4];
  const float* b1 = (const float*)d_in[5];
  const float* W2 = (const float*)d_in[6];
  const float* b2 = (const float*)d_in[7];
  float* out = (float*)d_out;
  float* proj = (float*)d_ws;  // 16000 floats = 64 KB scratch

  emb_proj_kernel<<<(TABN + 255) / 256, 256, 0, stream>>>(emb_table, W1, b1, proj);

  // 32768 chains * 4 lanes = 131072 threads; 512 blocks of 256 -> 2 blocks/CU
  scan_kernel<<<(BA * 4) / 256, 256, 0, stream>>>(
      c_Action, c_Reward, c_ParticipantID, W1, W2, b2, proj, out);
}